// Round 2
// baseline (485.123 us; speedup 1.0000x reference)
//
#include <hip/hip_runtime.h>

#define NROW   1024
#define ROWLEN 9216
#define NGRP   1024
#define NT     256
#define GPT    4            // groups per thread (1024/256)
#define NLEAF  128          // numpy pairwise leaves: 9216 = 128 x 72

__global__ __launch_bounds__(NT) void squant_kernel(const float* __restrict__ w,
                                                    float* __restrict__ out) {
    // s_buf4: Phase A = fp32 weight row; Phase B onward = post-pass-1 err (f32);
    //         fallback (never in practice) = dense candidate scratch.
    __shared__ float4 s_buf4[ROWLEN / 4];     // 36864 B
    __shared__ signed char s_r2[ROWLEN];      //  9216 B  post-pass-1 rounded ints
    __shared__ unsigned short s_upos[NGRP];   //  2048 B  sparse handoff positions (up)
    __shared__ unsigned short s_dpos[NGRP];   //  2048 B
    __shared__ float s_uval[NGRP];            //  4096 B  sparse handoff priorities (up)
    __shared__ float s_dval[NGRP];            //  4096 B
    __shared__ signed char s_ucn[NGRP];       //  1024 B  value to write if entry flips (up)
    __shared__ signed char s_dcn[NGRP];       //  1024 B
    __shared__ float s_leaf[NLEAF];           //   512 B  numpy pairwise leaf sums
    __shared__ float s_redf[NT];              //  1024 B
    __shared__ int   s_redi[NT];              //  1024 B
    __shared__ float s_bc[2];                 // xmin, xmax          => total 62984 B

    float* s_err = (float*)s_buf4;
    const int row = blockIdx.x;
    const int tid = threadIdx.x;
    const float* wrow = w + (size_t)row * ROWLEN;

    // ---------- Phase A: load fp32 row into LDS + min/max ----------
    float vmin =  3.402823466e38f;
    float vmax = -3.402823466e38f;
    const float4* w4 = reinterpret_cast<const float4*>(wrow);
    #pragma unroll
    for (int k = 0; k < ROWLEN / 4 / NT; ++k) {     // 9 iters, 16B/lane coalesced
        int i = tid + k * NT;
        float4 v = w4[i];
        s_buf4[i] = v;
        vmin = fminf(vmin, fminf(fminf(v.x, v.y), fminf(v.z, v.w)));
        vmax = fmaxf(vmax, fmaxf(fmaxf(v.x, v.y), fmaxf(v.z, v.w)));
    }
    s_redf[tid] = vmin; __syncthreads();
    for (int s = NT / 2; s > 0; s >>= 1) {
        if (tid < s) s_redf[tid] = fminf(s_redf[tid], s_redf[tid + s]);
        __syncthreads();
    }
    if (tid == 0) s_bc[0] = s_redf[0];
    __syncthreads();
    s_redf[tid] = vmax; __syncthreads();
    for (int s = NT / 2; s > 0; s >>= 1) {
        if (tid < s) s_redf[tid] = fmaxf(s_redf[tid], s_redf[tid + s]);
        __syncthreads();
    }
    if (tid == 0) s_bc[1] = s_redf[0];
    __syncthreads();

    const float xmin  = s_bc[0];
    const float xmax  = s_bc[1];
    const float scale = __fdiv_rn(15.0f, fmaxf(__fsub_rn(xmax, xmin), 1e-8f));
    const float zp    = __fadd_rn(rintf(__fmul_rn(scale, xmin)), 8.0f);

    // ---------- Phase B: pass 1 (per 9-element kernel group) ----------
    // Thread t exclusively owns elements [36t, 36t+36): reads w from s_err,
    // overwrites the same slots with post-pass-1 err.
    for (int gi = 0; gi < GPT; ++gi) {
        const int g = tid * GPT + gi;
        const int base = g * 9;
        float q[9], r[9], err[9], pri[9];
        #pragma unroll
        for (int j = 0; j < 9; ++j) {
            float wv = s_err[base + j];
            float qq = __fsub_rn(__fmul_rn(scale, wv), zp);   // no fma: numpy mul-then-sub
            float rr = rintf(qq);                              // half-even == np.round
            q[j] = qq; r[j] = rr; err[j] = __fsub_rn(rr, qq);
        }
        // numpy pairwise order for n=9
        float e = __fadd_rn(
                    __fadd_rn(__fadd_rn(__fadd_rn(err[0], err[1]), __fadd_rn(err[2], err[3])),
                              __fadd_rn(__fadd_rn(err[4], err[5]), __fadd_rn(err[6], err[7]))),
                    err[8]);
        int nflip = (int)rintf(fabsf(e));
        const bool isup = (e < 0.0f);
        #pragma unroll
        for (int j = 0; j < 9; ++j) {
            bool cand = isup ? ((err[j] < 0.0f) && (q[j] < 7.0f))
                             : ((err[j] > 0.0f) && (q[j] > -8.0f));
            pri[j] = cand ? (isup ? -err[j] : err[j]) : 0.0f;   // cand <=> pri>0
        }
        const int nf  = nflip < 9 ? nflip : 9;
        const int nip = nf < 8 ? nf : 8;                        // clip(nflip, 0, 8)
        int lip = nf - 1; if (lip < 0) lip = 0;                 // clip(nflip-1, 0, 8)

        int ni = 0, li = 0;
        float pri_ni = 0.0f, pri_li = 0.0f, r_ni = 0.0f, r_li = 0.0f;
        #pragma unroll
        for (int j = 0; j < 9; ++j) {
            // stable descending rank (ties -> lower index), == np argsort (insertion, n<=16)
            int rank = 0;
            #pragma unroll
            for (int k = 0; k < 9; ++k)
                rank += (int)((pri[k] > pri[j]) || ((pri[k] == pri[j]) && (k < j)));
            bool cand = pri[j] > 0.0f;
            bool flip = rank < nf;
            float cnj = cand ? (isup ? r[j] + 1.0f : r[j] - 1.0f) : r[j];
            float cej = cand ? (isup ? __fadd_rn(err[j], 1.0f) : __fsub_rn(err[j], 1.0f)) : 0.0f;
            s_r2[base + j]  = (signed char)__float2int_rn(flip ? cnj : r[j]);
            s_err[base + j] = flip ? cej : err[j];              // own slot: w -> err2
            if (rank == nip) { ni = j; pri_ni = pri[j]; r_ni = r[j]; }
            if (rank == lip) { li = j; pri_li = pri[j]; r_li = r[j]; }
        }
        const bool has_next = (nflip < 9);
        const bool has_last = (nflip > 0);
        const float next_pri = has_next ? pri_ni : 0.0f;
        const float last_pri = has_last ? __fsub_rn(1.0f, pri_li) : 0.0f;
        // value if the next-candidate entry flips in pass 2 (direction of this row)
        signed char ncv = (signed char)__float2int_rn(
            (pri_ni > 0.0f) ? (isup ? r_ni + 1.0f : r_ni - 1.0f) : r_ni);
        // value if the revert entry flips in pass 2 (restores pre-flip r)
        signed char lcv = (signed char)__float2int_rn(r_li);
        if (isup) {
            s_upos[g] = (unsigned short)(base + ni); s_uval[g] = next_pri; s_ucn[g] = ncv;
            s_dpos[g] = (unsigned short)(base + li); s_dval[g] = last_pri; s_dcn[g] = lcv;
        } else {
            s_dpos[g] = (unsigned short)(base + ni); s_dval[g] = next_pri; s_dcn[g] = ncv;
            s_upos[g] = (unsigned short)(base + li); s_uval[g] = last_pri; s_ucn[g] = lcv;
        }
    }
    __syncthreads();

    // ---------- e2: numpy float32 pairwise sum over 9216 = 128 leaves of 72 ----------
    if (tid < NLEAF) {
        const float* a = s_err + tid * 72;
        float acc[8];
        #pragma unroll
        for (int j = 0; j < 8; ++j) acc[j] = a[j];
        for (int i = 8; i < 72; i += 8) {
            #pragma unroll
            for (int j = 0; j < 8; ++j) acc[j] = __fadd_rn(acc[j], a[i + j]);
        }
        s_leaf[tid] = __fadd_rn(__fadd_rn(__fadd_rn(acc[0], acc[1]), __fadd_rn(acc[2], acc[3])),
                                __fadd_rn(__fadd_rn(acc[4], acc[5]), __fadd_rn(acc[6], acc[7])));
    }
    __syncthreads();
    for (int s = 1; s < NLEAF; s <<= 1) {      // balanced binary combine == numpy recursion
        if (tid < NLEAF && (tid & (2 * s - 1)) == 0)
            s_leaf[tid] = __fadd_rn(s_leaf[tid], s_leaf[tid + s]);
        __syncthreads();
    }
    const float e2     = s_leaf[0];
    const int   nflip2 = (int)rintf(fabsf(e2));
    const bool  isup2  = (e2 < 0.0f);

    const float* val = isup2 ? s_uval : s_dval;
    const unsigned short* pos = isup2 ? s_upos : s_dpos;
    const signed char* cnv = isup2 ? s_ucn : s_dcn;

    // ---------- Phase C: pass 2 — stable top-nflip2 over sparse entries ----------
    // entry order == dense position order (pos[g] in [9g,9g+9)), so j<ei tie-break is exact
    int ei[4]; float vi[4]; int rk[4];
    #pragma unroll
    for (int m = 0; m < 4; ++m) { ei[m] = tid + m * NT; vi[m] = val[ei[m]]; rk[m] = 0; }
    int nposl = 0;
    #pragma unroll
    for (int m = 0; m < 4; ++m) nposl += (vi[m] > 0.0f) ? 1 : 0;
    if (nflip2 > 0) {
        for (int j = 0; j < NGRP; ++j) {
            float vj = val[j];                 // LDS broadcast: same addr all lanes
            #pragma unroll
            for (int m = 0; m < 4; ++m)
                rk[m] += (int)((vj > vi[m]) || ((vj == vi[m]) && (j < ei[m])));
        }
        #pragma unroll
        for (int m = 0; m < 4; ++m)
            if (vi[m] > 0.0f && rk[m] < nflip2) s_r2[pos[ei[m]]] = cnv[ei[m]];
    }
    __syncthreads();
    s_redi[tid] = nposl; __syncthreads();
    for (int s = NT / 2; s > 0; s >>= 1) {
        if (tid < s) s_redi[tid] += s_redi[tid + s];
        __syncthreads();
    }
    const int extra = nflip2 - s_redi[0];

    if (extra > 0) {   // ~never: selection spills into zero-priority elements
        signed char*  s_upn  = (signed char*)s_err;
        signed char*  s_dnn  = (signed char*)s_err + ROWLEN;
        unsigned char* s_flag = (unsigned char*)s_err + 2 * ROWLEN;
        for (int i = tid; i < ROWLEN; i += NT) s_flag[i] = 0;
        __syncthreads();
        // recompute dense candidate arrays (incl. pass-1 reverts) from global w
        for (int gi = 0; gi < GPT; ++gi) {
            const int base = (tid * GPT + gi) * 9;
            float q[9], r[9], err[9], pri[9];
            #pragma unroll
            for (int j = 0; j < 9; ++j) {
                float wv = wrow[base + j];
                float qq = __fsub_rn(__fmul_rn(scale, wv), zp);
                float rr = rintf(qq);
                q[j] = qq; r[j] = rr; err[j] = __fsub_rn(rr, qq);
            }
            float e = __fadd_rn(
                        __fadd_rn(__fadd_rn(__fadd_rn(err[0], err[1]), __fadd_rn(err[2], err[3])),
                                  __fadd_rn(__fadd_rn(err[4], err[5]), __fadd_rn(err[6], err[7]))),
                        err[8]);
            int nflip = (int)rintf(fabsf(e));
            const bool isup = (e < 0.0f);
            #pragma unroll
            for (int j = 0; j < 9; ++j) {
                bool cand = isup ? ((err[j] < 0.0f) && (q[j] < 7.0f))
                                 : ((err[j] > 0.0f) && (q[j] > -8.0f));
                pri[j] = cand ? (isup ? -err[j] : err[j]) : 0.0f;
            }
            const int nf = nflip < 9 ? nflip : 9;
            int lip = nf - 1; if (lip < 0) lip = 0;
            int li = 0;
            #pragma unroll
            for (int j = 0; j < 9; ++j) {
                int rank = 0;
                #pragma unroll
                for (int k = 0; k < 9; ++k)
                    rank += (int)((pri[k] > pri[j]) || ((pri[k] == pri[j]) && (k < j)));
                bool cu = (err[j] < 0.0f) && (q[j] < 7.0f);
                bool cd = (err[j] > 0.0f) && (q[j] > -8.0f);
                s_upn[base + j] = (signed char)__float2int_rn(cu ? r[j] + 1.0f : r[j]);
                s_dnn[base + j] = (signed char)__float2int_rn(cd ? r[j] - 1.0f : r[j]);
                if (rank == lip) li = j;
            }
            if (nflip > 0) {   // revert slot on the opposite side
                if (isup) s_dnn[base + li] = (signed char)__float2int_rn(r[li]);
                else      s_upn[base + li] = (signed char)__float2int_rn(r[li]);
            }
        }
        for (int e2i = tid; e2i < NGRP; e2i += NT)
            if (val[e2i] > 0.0f) s_flag[pos[e2i]] = 1;
        __syncthreads();
        if (tid == 0) {
            int c = 0;
            for (int p = 0; p < ROWLEN && c < extra; ++p)
                if (!s_flag[p]) { s_r2[p] = isup2 ? s_upn[p] : s_dnn[p]; ++c; }
        }
    }
    __syncthreads();

    // ---------- epilogue: clip + dequantize + fp32 store ----------
    float4* o4 = reinterpret_cast<float4*>(out + (size_t)row * ROWLEN);
    #pragma unroll
    for (int k = 0; k < ROWLEN / 4 / NT; ++k) {
        int i = tid + k * NT;
        int b = i * 4;
        int v0 = s_r2[b + 0], v1 = s_r2[b + 1], v2 = s_r2[b + 2], v3 = s_r2[b + 3];
        v0 = v0 < -8 ? -8 : (v0 > 7 ? 7 : v0);
        v1 = v1 < -8 ? -8 : (v1 > 7 ? 7 : v1);
        v2 = v2 < -8 ? -8 : (v2 > 7 ? 7 : v2);
        v3 = v3 < -8 ? -8 : (v3 > 7 ? 7 : v3);
        float4 o;
        o.x = __fdiv_rn(__fadd_rn((float)v0, zp), scale);
        o.y = __fdiv_rn(__fadd_rn((float)v1, zp), scale);
        o.z = __fdiv_rn(__fadd_rn((float)v2, zp), scale);
        o.w = __fdiv_rn(__fadd_rn((float)v3, zp), scale);
        o4[i] = o;
    }
}

extern "C" void kernel_launch(void* const* d_in, const int* in_sizes, int n_in,
                              void* d_out, int out_size, void* d_ws, size_t ws_size,
                              hipStream_t stream) {
    const float* w = (const float*)d_in[0];
    float* out = (float*)d_out;
    squant_kernel<<<dim3(NROW), dim3(NT), 0, stream>>>(w, out);
}

// Round 3
// 105.613 us; speedup vs baseline: 4.5934x; 4.5934x over previous
//
#include <hip/hip_runtime.h>

#define NROW   1024
#define ROWLEN 9216
#define NGRP   1024
#define NT     512
#define GPT    2            // groups per thread (1024/512)
#define NLEAF  128          // numpy pairwise leaves: 9216 = 128 x 72
#define LCAP   256          // boundary-bucket list capacity

__device__ __forceinline__ int bucketOf(float v) {   // monotone, equal v -> equal bucket
    int b = (int)(v * 256.0f);
    return b > 255 ? 255 : b;
}

__global__ __launch_bounds__(NT, 4) void squant_kernel(const float* __restrict__ w,
                                                       float* __restrict__ out) {
    __shared__ float4 s_buf4[ROWLEN / 4];     // 36864 B: Phase A = w row; Phase B+ = err
    __shared__ signed char s_r2[ROWLEN];      //  9216 B  post-pass-1 rounded ints
    __shared__ unsigned short s_upos[NGRP];   //  2048 B
    __shared__ unsigned short s_dpos[NGRP];   //  2048 B
    __shared__ float s_uval[NGRP];            //  4096 B
    __shared__ float s_dval[NGRP];            //  4096 B
    __shared__ signed char s_ucn[NGRP];       //  1024 B
    __shared__ signed char s_dcn[NGRP];       //  1024 B
    __shared__ float s_leaf[NLEAF];           //   512 B
    __shared__ int   s_hist[256];             //  1024 B
    __shared__ float s_lv[LCAP];              //  1024 B  boundary-bucket values
    __shared__ unsigned short s_lg[LCAP];     //   512 B  boundary-bucket entry indices
    __shared__ float s_wred[16];              //    64 B  wave partials (min | max)
    __shared__ float s_bc[2];                 // xmin, xmax
    __shared__ int   s_seli[2];               // cutoff bucket B, in-bucket count m
    __shared__ int   s_lcount;                // total ~63.6 KB

    float* s_err = (float*)s_buf4;
    const int row = blockIdx.x;
    const int tid = threadIdx.x;
    const int lane = tid & 63, wid = tid >> 6;
    const float* wrow = w + (size_t)row * ROWLEN;

    // ---------- Phase A: load fp32 row into LDS + min/max ----------
    float vmin =  3.402823466e38f;
    float vmax = -3.402823466e38f;
    const float4* w4 = reinterpret_cast<const float4*>(wrow);
    #pragma unroll
    for (int k = 0; k < 4; ++k) {                  // 4*512 = 2048 of 2304 vec4s
        int i = tid + k * NT;
        float4 v = w4[i];
        s_buf4[i] = v;
        vmin = fminf(vmin, fminf(fminf(v.x, v.y), fminf(v.z, v.w)));
        vmax = fmaxf(vmax, fmaxf(fmaxf(v.x, v.y), fmaxf(v.z, v.w)));
    }
    if (tid < 256) {                               // remainder 256 vec4s
        int i = 2048 + tid;
        float4 v = w4[i];
        s_buf4[i] = v;
        vmin = fminf(vmin, fminf(fminf(v.x, v.y), fminf(v.z, v.w)));
        vmax = fmaxf(vmax, fmaxf(fmaxf(v.x, v.y), fmaxf(v.z, v.w)));
    }
    #pragma unroll
    for (int o = 32; o > 0; o >>= 1) {             // wave64 xor-reduce
        vmin = fminf(vmin, __shfl_xor(vmin, o, 64));
        vmax = fmaxf(vmax, __shfl_xor(vmax, o, 64));
    }
    if (lane == 0) { s_wred[wid] = vmin; s_wred[8 + wid] = vmax; }
    __syncthreads();
    if (tid == 0) {
        float a = s_wred[0], b = s_wred[8];
        #pragma unroll
        for (int i = 1; i < 8; ++i) { a = fminf(a, s_wred[i]); b = fmaxf(b, s_wred[8 + i]); }
        s_bc[0] = a; s_bc[1] = b;
    }
    __syncthreads();

    const float xmin  = s_bc[0];
    const float xmax  = s_bc[1];
    const float scale = __fdiv_rn(15.0f, fmaxf(__fsub_rn(xmax, xmin), 1e-8f));
    const float zp    = __fadd_rn(rintf(__fmul_rn(scale, xmin)), 8.0f);

    // ---------- Phase B: pass 1 (per 9-element kernel group) ----------
    // Thread t exclusively owns elements [18t, 18t+18): reads w, overwrites with err.
    for (int gi = 0; gi < GPT; ++gi) {
        const int g = tid * GPT + gi;
        const int base = g * 9;
        float q[9], r[9], err[9], pri[9];
        #pragma unroll
        for (int j = 0; j < 9; ++j) {
            float wv = s_err[base + j];
            float qq = __fsub_rn(__fmul_rn(scale, wv), zp);   // no fma: numpy mul-then-sub
            float rr = rintf(qq);                              // half-even == np.round
            q[j] = qq; r[j] = rr; err[j] = __fsub_rn(rr, qq);
        }
        float e = __fadd_rn(
                    __fadd_rn(__fadd_rn(__fadd_rn(err[0], err[1]), __fadd_rn(err[2], err[3])),
                              __fadd_rn(__fadd_rn(err[4], err[5]), __fadd_rn(err[6], err[7]))),
                    err[8]);
        int nflip = (int)rintf(fabsf(e));
        const bool isup = (e < 0.0f);
        #pragma unroll
        for (int j = 0; j < 9; ++j) {
            bool cand = isup ? ((err[j] < 0.0f) && (q[j] < 7.0f))
                             : ((err[j] > 0.0f) && (q[j] > -8.0f));
            pri[j] = cand ? (isup ? -err[j] : err[j]) : 0.0f;   // cand <=> pri>0
        }
        // stable descending ranks via pairwise total order: for a<b, a beats b iff pri[a]>=pri[b]
        int rank[9] = {0,0,0,0,0,0,0,0,0};
        #pragma unroll
        for (int a = 0; a < 9; ++a)
            #pragma unroll
            for (int b = a + 1; b < 9; ++b) {
                int c = (pri[a] >= pri[b]) ? 1 : 0;
                rank[b] += c;
                rank[a] += 1 - c;
            }
        const int nf  = nflip < 9 ? nflip : 9;
        const int nip = nf < 8 ? nf : 8;
        int lip = nf - 1; if (lip < 0) lip = 0;

        int ni = 0, li = 0;
        float pri_ni = 0.0f, pri_li = 0.0f, r_ni = 0.0f, r_li = 0.0f;
        #pragma unroll
        for (int j = 0; j < 9; ++j) {
            bool cand = pri[j] > 0.0f;
            bool flip = rank[j] < nf;
            float cnj = cand ? (isup ? r[j] + 1.0f : r[j] - 1.0f) : r[j];
            float cej = cand ? (isup ? __fadd_rn(err[j], 1.0f) : __fsub_rn(err[j], 1.0f)) : 0.0f;
            s_r2[base + j]  = (signed char)__float2int_rn(flip ? cnj : r[j]);
            s_err[base + j] = flip ? cej : err[j];
            if (rank[j] == nip) { ni = j; pri_ni = pri[j]; r_ni = r[j]; }
            if (rank[j] == lip) { li = j; pri_li = pri[j]; r_li = r[j]; }
        }
        const bool has_next = (nflip < 9);
        const bool has_last = (nflip > 0);
        const float next_pri = has_next ? pri_ni : 0.0f;
        const float last_pri = has_last ? __fsub_rn(1.0f, pri_li) : 0.0f;
        signed char ncv = (signed char)__float2int_rn(
            (pri_ni > 0.0f) ? (isup ? r_ni + 1.0f : r_ni - 1.0f) : r_ni);
        signed char lcv = (signed char)__float2int_rn(r_li);
        if (isup) {
            s_upos[g] = (unsigned short)(base + ni); s_uval[g] = next_pri; s_ucn[g] = ncv;
            s_dpos[g] = (unsigned short)(base + li); s_dval[g] = last_pri; s_dcn[g] = lcv;
        } else {
            s_dpos[g] = (unsigned short)(base + ni); s_dval[g] = next_pri; s_dcn[g] = ncv;
            s_upos[g] = (unsigned short)(base + li); s_uval[g] = last_pri; s_ucn[g] = lcv;
        }
    }
    __syncthreads();

    // ---------- e2: numpy float32 pairwise sum (9216 = 128 leaves x 72) ----------
    if (tid < NLEAF) {
        const float* a = s_err + tid * 72;
        float acc[8];
        #pragma unroll
        for (int j = 0; j < 8; ++j) acc[j] = a[j];
        for (int i = 8; i < 72; i += 8) {
            #pragma unroll
            for (int j = 0; j < 8; ++j) acc[j] = __fadd_rn(acc[j], a[i + j]);
        }
        s_leaf[tid] = __fadd_rn(__fadd_rn(__fadd_rn(acc[0], acc[1]), __fadd_rn(acc[2], acc[3])),
                                __fadd_rn(__fadd_rn(acc[4], acc[5]), __fadd_rn(acc[6], acc[7])));
    }
    __syncthreads();
    for (int s = 1; s < NLEAF; s <<= 1) {
        if (tid < NLEAF && (tid & (2 * s - 1)) == 0)
            s_leaf[tid] = __fadd_rn(s_leaf[tid], s_leaf[tid + s]);
        __syncthreads();
    }
    const float e2     = s_leaf[0];
    const int   nflip2 = (int)rintf(fabsf(e2));
    const bool  isup2  = (e2 < 0.0f);

    const float* val = isup2 ? s_uval : s_dval;
    const unsigned short* pos = isup2 ? s_upos : s_dpos;
    const signed char* cnv = isup2 ? s_ucn : s_dcn;

    // ---------- Phase C: stable top-nflip2 via 256-bucket histogram select ----------
    if (tid < 256) s_hist[tid] = 0;
    if (tid == 0) s_lcount = 0;
    __syncthreads();

    const int g0 = tid, g1 = tid + NT;            // stride-1 LDS, conflict-free
    const float v0 = val[g0], v1 = val[g1];
    const int b0 = (v0 > 0.0f) ? bucketOf(v0) : -1;
    const int b1 = (v1 > 0.0f) ? bucketOf(v1) : -1;
    if (b0 >= 0) atomicAdd(&s_hist[b0], 1);
    if (b1 >= 0) atomicAdd(&s_hist[b1], 1);
    __syncthreads();
    for (int s = 1; s < 256; s <<= 1) {           // suffix scan: s_hist[b] = #{bucket >= b}
        int t = 0;
        if (tid < 256) t = s_hist[tid] + ((tid + s < 256) ? s_hist[tid + s] : 0);
        __syncthreads();
        if (tid < 256) s_hist[tid] = t;
        __syncthreads();
    }
    const int npos = s_hist[0];

    if (nflip2 > 0 && nflip2 <= npos) {
        if (tid < 256) {                          // unique cutoff bucket B
            int Tb  = s_hist[tid];
            int Tb1 = (tid < 255) ? s_hist[tid + 1] : 0;
            if (Tb >= nflip2 && Tb1 < nflip2) { s_seli[0] = tid; s_seli[1] = nflip2 - Tb1; }
        }
        __syncthreads();
        const int B = s_seli[0], m = s_seli[1];   // 1 <= m <= count(B)
        // flip all strictly-above-cutoff entries (all strictly greater values); compact bucket B
        if (b0 > B) s_r2[pos[g0]] = cnv[g0];
        else if (b0 == B) { int ix = atomicAdd(&s_lcount, 1);
                            if (ix < LCAP) { s_lv[ix] = v0; s_lg[ix] = (unsigned short)g0; } }
        if (b1 > B) s_r2[pos[g1]] = cnv[g1];
        else if (b1 == B) { int ix = atomicAdd(&s_lcount, 1);
                            if (ix < LCAP) { s_lv[ix] = v1; s_lg[ix] = (unsigned short)g1; } }
        __syncthreads();
        const int L = s_lcount;
        if (L <= LCAP) {                          // exact stable rank within boundary bucket
            if (b0 == B) {
                int rk = 0;
                for (int l = 0; l < L; ++l) {
                    float lv = s_lv[l]; int lg = s_lg[l];
                    rk += (int)((lv > v0) || ((lv == v0) && (lg < g0)));
                }
                if (rk < m) s_r2[pos[g0]] = cnv[g0];
            }
            if (b1 == B) {
                int rk = 0;
                for (int l = 0; l < L; ++l) {
                    float lv = s_lv[l]; int lg = s_lg[l];
                    rk += (int)((lv > v1) || ((lv == v1) && (lg < g1)));
                }
                if (rk < m) s_r2[pos[g1]] = cnv[g1];
            }
        } else {                                  // degenerate tie flood: full comparator scan
            if (b0 == B) {
                int rk = 0;
                for (int j = 0; j < NGRP; ++j) {
                    float vj = val[j];
                    if (vj > 0.0f && bucketOf(vj) == B)
                        rk += (int)((vj > v0) || ((vj == v0) && (j < g0)));
                }
                if (rk < m) s_r2[pos[g0]] = cnv[g0];
            }
            if (b1 == B) {
                int rk = 0;
                for (int j = 0; j < NGRP; ++j) {
                    float vj = val[j];
                    if (vj > 0.0f && bucketOf(vj) == B)
                        rk += (int)((vj > v1) || ((vj == v1) && (j < g1)));
                }
                if (rk < m) s_r2[pos[g1]] = cnv[g1];
            }
        }
    } else if (nflip2 > npos) {
        // all positives flip; remaining flips spill into zero-priority dense positions
        if (b0 >= 0) s_r2[pos[g0]] = cnv[g0];
        if (b1 >= 0) s_r2[pos[g1]] = cnv[g1];
        const int extra = nflip2 - npos;
        signed char*  s_upn  = (signed char*)s_err;
        signed char*  s_dnn  = (signed char*)s_err + ROWLEN;
        unsigned char* s_flag = (unsigned char*)s_err + 2 * ROWLEN;
        for (int i = tid; i < ROWLEN; i += NT) s_flag[i] = 0;
        __syncthreads();
        for (int gi = 0; gi < GPT; ++gi) {        // dense candidate recompute (incl. reverts)
            const int base = (tid * GPT + gi) * 9;
            float q[9], r[9], err[9], pri[9];
            #pragma unroll
            for (int j = 0; j < 9; ++j) {
                float wv = wrow[base + j];
                float qq = __fsub_rn(__fmul_rn(scale, wv), zp);
                float rr = rintf(qq);
                q[j] = qq; r[j] = rr; err[j] = __fsub_rn(rr, qq);
            }
            float e = __fadd_rn(
                        __fadd_rn(__fadd_rn(__fadd_rn(err[0], err[1]), __fadd_rn(err[2], err[3])),
                                  __fadd_rn(__fadd_rn(err[4], err[5]), __fadd_rn(err[6], err[7]))),
                        err[8]);
            int nflip = (int)rintf(fabsf(e));
            const bool isup = (e < 0.0f);
            #pragma unroll
            for (int j = 0; j < 9; ++j) {
                bool cand = isup ? ((err[j] < 0.0f) && (q[j] < 7.0f))
                                 : ((err[j] > 0.0f) && (q[j] > -8.0f));
                pri[j] = cand ? (isup ? -err[j] : err[j]) : 0.0f;
            }
            int rank[9] = {0,0,0,0,0,0,0,0,0};
            #pragma unroll
            for (int a = 0; a < 9; ++a)
                #pragma unroll
                for (int b = a + 1; b < 9; ++b) {
                    int c = (pri[a] >= pri[b]) ? 1 : 0;
                    rank[b] += c; rank[a] += 1 - c;
                }
            const int nf = nflip < 9 ? nflip : 9;
            int lip = nf - 1; if (lip < 0) lip = 0;
            int li = 0;
            #pragma unroll
            for (int j = 0; j < 9; ++j) {
                bool cu = (err[j] < 0.0f) && (q[j] < 7.0f);
                bool cd = (err[j] > 0.0f) && (q[j] > -8.0f);
                s_upn[base + j] = (signed char)__float2int_rn(cu ? r[j] + 1.0f : r[j]);
                s_dnn[base + j] = (signed char)__float2int_rn(cd ? r[j] - 1.0f : r[j]);
                if (rank[j] == lip) li = j;
            }
            if (nflip > 0) {
                if (isup) s_dnn[base + li] = (signed char)__float2int_rn(r[li]);
                else      s_upn[base + li] = (signed char)__float2int_rn(r[li]);
            }
        }
        for (int e2i = tid; e2i < NGRP; e2i += NT)
            if (val[e2i] > 0.0f) s_flag[pos[e2i]] = 1;
        __syncthreads();
        if (tid == 0) {
            int c = 0;
            for (int p = 0; p < ROWLEN && c < extra; ++p)
                if (!s_flag[p]) { s_r2[p] = isup2 ? s_upn[p] : s_dnn[p]; ++c; }
        }
    }
    __syncthreads();

    // ---------- epilogue: clip + dequantize + fp32 store ----------
    float4* o4 = reinterpret_cast<float4*>(out + (size_t)row * ROWLEN);
    #pragma unroll
    for (int k = 0; k < 5; ++k) {
        int i = tid + k * NT;
        if (k == 4 && tid >= 256) break;
        int b = i * 4;
        int v0i = s_r2[b + 0], v1i = s_r2[b + 1], v2i = s_r2[b + 2], v3i = s_r2[b + 3];
        v0i = v0i < -8 ? -8 : (v0i > 7 ? 7 : v0i);
        v1i = v1i < -8 ? -8 : (v1i > 7 ? 7 : v1i);
        v2i = v2i < -8 ? -8 : (v2i > 7 ? 7 : v2i);
        v3i = v3i < -8 ? -8 : (v3i > 7 ? 7 : v3i);
        float4 o;
        o.x = __fdiv_rn(__fadd_rn((float)v0i, zp), scale);
        o.y = __fdiv_rn(__fadd_rn((float)v1i, zp), scale);
        o.z = __fdiv_rn(__fadd_rn((float)v2i, zp), scale);
        o.w = __fdiv_rn(__fadd_rn((float)v3i, zp), scale);
        o4[i] = o;
    }
}

extern "C" void kernel_launch(void* const* d_in, const int* in_sizes, int n_in,
                              void* d_out, int out_size, void* d_ws, size_t ws_size,
                              hipStream_t stream) {
    const float* w = (const float*)d_in[0];
    float* out = (float*)d_out;
    squant_kernel<<<dim3(NROW), dim3(NT), 0, stream>>>(w, out);
}